// Round 3
// baseline (283.711 us; speedup 1.0000x reference)
//
#include <hip/hip_runtime.h>

// x volumes: [256,256,256] fp32. Row (d,h) = 256 floats = 64 float4.
// float4-unit offset: d*16384 + h*64 + lane.
//
// R9: occupancy push. Four structures (10-VMEM no-LDS, LDS+syncthreads,
// LDS+fence-free, R8 barrier-free) all hit the same 45-49us floor; all pipe
// throughput models (VALU 12us, L1 10us, L2 11us, L3 16us, HBM 21us) are far
// below it; FETCH=77MB<128MB shows the data is L3-resident (warm==cold is
// expected). Remaining bound: exposed loaded-L2/L3 latency x concurrency.
// 65536 wave-steps / 110K cy = 430 cy/step/CU at only ~10 waves/CU (31%
// occupancy, grid was 4 blocks/CU) => ~4300cy queued latency per step that
// prefetch-distance-1 can't hide. Only TLP covers that.
// Fix: D_CHUNK 16->8, grid 1024->2048 = 8 blocks/CU = 32 waves/CU (100%),
// launch_bounds(256,8) (kernel is 60 VGPR, fits 8 waves/SIMD).
// R8 lesson: contiguous 1KB float4 loads only, no sparse edge loads.
// R3 lesson: no __threadfence / fused finalize (per-XCD L2 writeback storm).
//
// Grid: 64 htiles x 32 d-chunks (8 deep) = 2048 blocks x 256 thr, no loop LDS.

#define D_CHUNK 8

__global__ __launch_bounds__(256, 8) void grad_loss_kernel(const float* __restrict__ xf1,
                                                           const float* __restrict__ xf2,
                                                           double* __restrict__ acc) {
    const float4* __restrict__ x1 = (const float4*)xf1;
    const float4* __restrict__ x2 = (const float4*)xf2;

    const int tid  = threadIdx.x;
    const int lane = tid & 63;
    const int wid  = tid >> 6;          // 0..3

    // XCD-contiguous swizzle: 2048 blocks, 8 XCDs round-robin on raw
    // blockIdx. Remap so XCD k owns 256 consecutive work-ids = full h-range
    // of 4 adjacent d-chunks -> h-edge and d-edge overlap stays in one L2.
    const int orig = blockIdx.x;
    const int wg   = (orig & 7) * 256 + (orig >> 3);
    const int htile = wg & 63;          // 0..63
    const int dchk  = wg >> 6;          // 0..31

    const int  r    = 1 + htile * 4 + wid;          // 1..256
    const bool live = (r <= 254);
    const int  rc   = (r <= 255) ? r : 255;         // clamped own row
    const int  rm   = r - 1;                        // 0..255, always valid
    const int  rp   = (r + 1 <= 255) ? (r + 1) : 255;

    const int iU = rm * 64 + lane;      // row r-1
    const int iC = rc * 64 + lane;      // row r
    const int iV = rp * 64 + lane;      // row r+1

    const int d0 = 1 + dchk * D_CHUNK;  // computed depths d0..d0+7 (tail >254 dead)

    // per-voxel w-axis weights (0 = excluded border, 2 = edge-replicated)
    const float ww0 = (lane == 0)  ? 0.0f : 1.0f;   // w = 4*lane   (w==0)
    const float ww1 = (lane == 0)  ? 2.0f : 1.0f;   // w = 4*lane+1 (w==1)
    const float ww2 = (lane == 63) ? 2.0f : 1.0f;   // w = 4*lane+2 (w==254)
    const float ww3 = (lane == 63) ? 0.0f : 1.0f;   // w = 4*lane+3 (w==255)
    const float whf = (r == 1 || r == 254) ? 2.0f : 1.0f;

    // ---- prologue: plane d0-1 own row; planes d0, d0+1 all 3 rows.
    float4 a1  = x1[(d0 - 1) * 16384 + iC];
    float4 a2  = x2[(d0 - 1) * 16384 + iC];
    float4 bU1 = x1[d0 * 16384 + iU];
    float4 bC1 = x1[d0 * 16384 + iC];
    float4 bV1 = x1[d0 * 16384 + iV];
    float4 bU2 = x2[d0 * 16384 + iU];
    float4 bC2 = x2[d0 * 16384 + iC];
    float4 bV2 = x2[d0 * 16384 + iV];
    float4 cU1 = x1[(d0 + 1) * 16384 + iU];   // d0+1 <= 250 always
    float4 cC1 = x1[(d0 + 1) * 16384 + iC];
    float4 cV1 = x1[(d0 + 1) * 16384 + iV];
    float4 cU2 = x2[(d0 + 1) * 16384 + iU];
    float4 cC2 = x2[(d0 + 1) * 16384 + iC];
    float4 cV2 = x2[(d0 + 1) * 16384 + iV];

    float val = 0.0f;

    #pragma unroll 2
    for (int i = 0; i < D_CHUNK; ++i) {
        const int d  = d0 + i;
        const int dn = (d + 2 <= 255) ? (d + 2) : 255;   // prefetch depth (clamped tail)
        const int off = dn * 16384;

        // prefetch plane d+2, rows r-1/r/r+1, both inputs (consumed next step)
        float4 qU1 = x1[off + iU];
        float4 qC1 = x1[off + iC];
        float4 qV1 = x1[off + iV];
        float4 qU2 = x2[off + iU];
        float4 qC2 = x2[off + iC];
        float4 qV2 = x2[off + iV];

        if (live && d <= 254) {
            float l1 = __shfl_up(bC1.w, 1, 64);          // lane0: self -> finite, ww0=0
            float r1 = __shfl_down(bC1.x, 1, 64);        // lane63: self -> finite, ww3=0
            float l2 = __shfl_up(bC2.w, 1, 64);
            float r2 = __shfl_down(bC2.x, 1, 64);

            float gw, gd, gh;
            gw = cC1.x - a1.x; gd = bV1.x - bU1.x; gh = bC1.y - l1;
            float m10 = __builtin_amdgcn_sqrtf(gw * gw + gd * gd + gh * gh + 1e-6f);
            gw = cC1.y - a1.y; gd = bV1.y - bU1.y; gh = bC1.z - bC1.x;
            float m11 = __builtin_amdgcn_sqrtf(gw * gw + gd * gd + gh * gh + 1e-6f);
            gw = cC1.z - a1.z; gd = bV1.z - bU1.z; gh = bC1.w - bC1.y;
            float m12 = __builtin_amdgcn_sqrtf(gw * gw + gd * gd + gh * gh + 1e-6f);
            gw = cC1.w - a1.w; gd = bV1.w - bU1.w; gh = r1 - bC1.z;
            float m13 = __builtin_amdgcn_sqrtf(gw * gw + gd * gd + gh * gh + 1e-6f);

            gw = cC2.x - a2.x; gd = bV2.x - bU2.x; gh = bC2.y - l2;
            float m20 = __builtin_amdgcn_sqrtf(gw * gw + gd * gd + gh * gh + 1e-6f);
            gw = cC2.y - a2.y; gd = bV2.y - bU2.y; gh = bC2.z - bC2.x;
            float m21 = __builtin_amdgcn_sqrtf(gw * gw + gd * gd + gh * gh + 1e-6f);
            gw = cC2.z - a2.z; gd = bV2.z - bU2.z; gh = bC2.w - bC2.y;
            float m22 = __builtin_amdgcn_sqrtf(gw * gw + gd * gd + gh * gh + 1e-6f);
            gw = cC2.w - a2.w; gd = bV2.w - bU2.w; gh = r2 - bC2.z;
            float m23 = __builtin_amdgcn_sqrtf(gw * gw + gd * gd + gh * gh + 1e-6f);

            float inner = ww0 * fabsf(m10 - m20)
                        + ww1 * fabsf(m11 - m21)
                        + ww2 * fabsf(m12 - m22)
                        + ww3 * fabsf(m13 - m23);

            const float wdf = (d == 1 || d == 254) ? 2.0f : 1.0f;
            val += wdf * whf * inner;
        }

        // roll the depth pipeline (renames after unroll; vmcnt waits are
        // counted, landing before next step's first use of the q regs)
        a1 = bC1; bU1 = cU1; bC1 = cC1; bV1 = cV1; cU1 = qU1; cC1 = qC1; cV1 = qV1;
        a2 = bC2; bU2 = cU2; bC2 = cC2; bV2 = cV2; cU2 = qU2; cC2 = qC2; cV2 = qV2;
    }

    // wave-64 reduction
    for (int off = 32; off > 0; off >>= 1)
        val += __shfl_down(val, off, 64);

    __shared__ float smem[4];
    if (lane == 0) smem[wid] = val;
    __syncthreads();

    if (wid == 0) {
        float s = (lane < 4) ? smem[lane] : 0.0f;
        s += __shfl_down(s, 2, 64);
        s += __shfl_down(s, 1, 64);
        if (lane == 0)
            atomicAdd(&acc[blockIdx.x & 255], (double)s);   // no fence!
    }
}

__global__ void finalize_kernel(const double* __restrict__ acc, float* __restrict__ out) {
    double v = acc[threadIdx.x];   // 256 threads, one slot each
    for (int off = 32; off > 0; off >>= 1)
        v += __shfl_down(v, off, 64);

    __shared__ double smem[4];
    const int lid = threadIdx.x & 63;
    const int wid = threadIdx.x >> 6;
    if (lid == 0) smem[wid] = v;
    __syncthreads();

    if (threadIdx.x == 0) {
        double s = smem[0] + smem[1] + smem[2] + smem[3];
        out[0] = (float)(s / 16777216.0);   // mean over 256^3
    }
}

extern "C" void kernel_launch(void* const* d_in, const int* in_sizes, int n_in,
                              void* d_out, int out_size, void* d_ws, size_t ws_size,
                              hipStream_t stream) {
    const float* x1 = (const float*)d_in[0];
    const float* x2 = (const float*)d_in[1];
    float* out = (float*)d_out;
    double* acc = (double*)d_ws;   // 256 doubles = 2 KiB scratch

    hipMemsetAsync(d_ws, 0, 256 * sizeof(double), stream);
    grad_loss_kernel<<<64 * 32, 256, 0, stream>>>(x1, x2, acc);
    finalize_kernel<<<1, 256, 0, stream>>>(acc, out);
}

// Round 4
// 154.321 us; speedup vs baseline: 1.8384x; 1.8384x over previous
//
#include <hip/hip_runtime.h>

// x volumes: [256,256,256] fp32. Row (d,h) = 256 floats = 64 float4.
// float4-unit offset: d*16384 + h*64 + lane.
//
// R10: clean TLP retest. R9's launch_bounds(256,8) forced VGPR=32 and the
// 14-float4 pipeline spilled to scratch (WRITE_SIZE 0.03->319MB = scratch
// stores, FETCH 3x, VALUBusy 7%) -- occupancy DID reach 78%, but the spill
// confound swamped the latency test. This round: same structure, grid 2048
// (8 blocks/CU), but launch_bounds(256,4) which R8 proved compiles to 60
// VGPR spill-free; 60 rounds to 64 = 8 waves/SIMD, so actual allocation
// still admits 8 blocks/CU. Isolates TLP (R8 was 31% occ @ 4 blocks/CU).
// R8 lesson: contiguous 1KB float4 loads only, no sparse edge loads.
// R9 lesson: never force occupancy via launch_bounds min-waves; let the
// natural VGPR count set the cap, push TLP via grid size only.
// R3 lesson: no __threadfence / fused finalize (per-XCD L2 writeback storm).
//
// Grid: 64 htiles x 32 d-chunks (8 deep) = 2048 blocks x 256 thr, no loop LDS.

#define D_CHUNK 8

__global__ __launch_bounds__(256, 4) void grad_loss_kernel(const float* __restrict__ xf1,
                                                           const float* __restrict__ xf2,
                                                           double* __restrict__ acc) {
    const float4* __restrict__ x1 = (const float4*)xf1;
    const float4* __restrict__ x2 = (const float4*)xf2;

    const int tid  = threadIdx.x;
    const int lane = tid & 63;
    const int wid  = tid >> 6;          // 0..3

    // XCD-contiguous swizzle: 2048 blocks, 8 XCDs round-robin on raw
    // blockIdx. Remap so XCD k owns 256 consecutive work-ids = full h-range
    // of 4 adjacent d-chunks -> h-edge and d-edge overlap stays in one L2.
    const int orig = blockIdx.x;
    const int wg   = (orig & 7) * 256 + (orig >> 3);
    const int htile = wg & 63;          // 0..63
    const int dchk  = wg >> 6;          // 0..31

    const int  r    = 1 + htile * 4 + wid;          // 1..256
    const bool live = (r <= 254);
    const int  rc   = (r <= 255) ? r : 255;         // clamped own row
    const int  rm   = r - 1;                        // 0..255, always valid
    const int  rp   = (r + 1 <= 255) ? (r + 1) : 255;

    const int iU = rm * 64 + lane;      // row r-1
    const int iC = rc * 64 + lane;      // row r
    const int iV = rp * 64 + lane;      // row r+1

    const int d0 = 1 + dchk * D_CHUNK;  // computed depths d0..d0+7 (tail >254 dead)

    // per-voxel w-axis weights (0 = excluded border, 2 = edge-replicated)
    const float ww0 = (lane == 0)  ? 0.0f : 1.0f;   // w = 4*lane   (w==0)
    const float ww1 = (lane == 0)  ? 2.0f : 1.0f;   // w = 4*lane+1 (w==1)
    const float ww2 = (lane == 63) ? 2.0f : 1.0f;   // w = 4*lane+2 (w==254)
    const float ww3 = (lane == 63) ? 0.0f : 1.0f;   // w = 4*lane+3 (w==255)
    const float whf = (r == 1 || r == 254) ? 2.0f : 1.0f;

    // ---- prologue: plane d0-1 own row; planes d0, d0+1 all 3 rows.
    float4 a1  = x1[(d0 - 1) * 16384 + iC];
    float4 a2  = x2[(d0 - 1) * 16384 + iC];
    float4 bU1 = x1[d0 * 16384 + iU];
    float4 bC1 = x1[d0 * 16384 + iC];
    float4 bV1 = x1[d0 * 16384 + iV];
    float4 bU2 = x2[d0 * 16384 + iU];
    float4 bC2 = x2[d0 * 16384 + iC];
    float4 bV2 = x2[d0 * 16384 + iV];
    float4 cU1 = x1[(d0 + 1) * 16384 + iU];   // d0+1 <= 250 always
    float4 cC1 = x1[(d0 + 1) * 16384 + iC];
    float4 cV1 = x1[(d0 + 1) * 16384 + iV];
    float4 cU2 = x2[(d0 + 1) * 16384 + iU];
    float4 cC2 = x2[(d0 + 1) * 16384 + iC];
    float4 cV2 = x2[(d0 + 1) * 16384 + iV];

    float val = 0.0f;

    #pragma unroll 2
    for (int i = 0; i < D_CHUNK; ++i) {
        const int d  = d0 + i;
        const int dn = (d + 2 <= 255) ? (d + 2) : 255;   // prefetch depth (clamped tail)
        const int off = dn * 16384;

        // prefetch plane d+2, rows r-1/r/r+1, both inputs (consumed next step)
        float4 qU1 = x1[off + iU];
        float4 qC1 = x1[off + iC];
        float4 qV1 = x1[off + iV];
        float4 qU2 = x2[off + iU];
        float4 qC2 = x2[off + iC];
        float4 qV2 = x2[off + iV];

        if (live && d <= 254) {
            float l1 = __shfl_up(bC1.w, 1, 64);          // lane0: self -> finite, ww0=0
            float r1 = __shfl_down(bC1.x, 1, 64);        // lane63: self -> finite, ww3=0
            float l2 = __shfl_up(bC2.w, 1, 64);
            float r2 = __shfl_down(bC2.x, 1, 64);

            float gw, gd, gh;
            gw = cC1.x - a1.x; gd = bV1.x - bU1.x; gh = bC1.y - l1;
            float m10 = __builtin_amdgcn_sqrtf(gw * gw + gd * gd + gh * gh + 1e-6f);
            gw = cC1.y - a1.y; gd = bV1.y - bU1.y; gh = bC1.z - bC1.x;
            float m11 = __builtin_amdgcn_sqrtf(gw * gw + gd * gd + gh * gh + 1e-6f);
            gw = cC1.z - a1.z; gd = bV1.z - bU1.z; gh = bC1.w - bC1.y;
            float m12 = __builtin_amdgcn_sqrtf(gw * gw + gd * gd + gh * gh + 1e-6f);
            gw = cC1.w - a1.w; gd = bV1.w - bU1.w; gh = r1 - bC1.z;
            float m13 = __builtin_amdgcn_sqrtf(gw * gw + gd * gd + gh * gh + 1e-6f);

            gw = cC2.x - a2.x; gd = bV2.x - bU2.x; gh = bC2.y - l2;
            float m20 = __builtin_amdgcn_sqrtf(gw * gw + gd * gd + gh * gh + 1e-6f);
            gw = cC2.y - a2.y; gd = bV2.y - bU2.y; gh = bC2.z - bC2.x;
            float m21 = __builtin_amdgcn_sqrtf(gw * gw + gd * gd + gh * gh + 1e-6f);
            gw = cC2.z - a2.z; gd = bV2.z - bU2.z; gh = bC2.w - bC2.y;
            float m22 = __builtin_amdgcn_sqrtf(gw * gw + gd * gd + gh * gh + 1e-6f);
            gw = cC2.w - a2.w; gd = bV2.w - bU2.w; gh = r2 - bC2.z;
            float m23 = __builtin_amdgcn_sqrtf(gw * gw + gd * gd + gh * gh + 1e-6f);

            float inner = ww0 * fabsf(m10 - m20)
                        + ww1 * fabsf(m11 - m21)
                        + ww2 * fabsf(m12 - m22)
                        + ww3 * fabsf(m13 - m23);

            const float wdf = (d == 1 || d == 254) ? 2.0f : 1.0f;
            val += wdf * whf * inner;
        }

        // roll the depth pipeline (renames after unroll; vmcnt waits are
        // counted, landing before next step's first use of the q regs)
        a1 = bC1; bU1 = cU1; bC1 = cC1; bV1 = cV1; cU1 = qU1; cC1 = qC1; cV1 = qV1;
        a2 = bC2; bU2 = cU2; bC2 = cC2; bV2 = cV2; cU2 = qU2; cC2 = qC2; cV2 = qV2;
    }

    // wave-64 reduction
    for (int off = 32; off > 0; off >>= 1)
        val += __shfl_down(val, off, 64);

    __shared__ float smem[4];
    if (lane == 0) smem[wid] = val;
    __syncthreads();

    if (wid == 0) {
        float s = (lane < 4) ? smem[lane] : 0.0f;
        s += __shfl_down(s, 2, 64);
        s += __shfl_down(s, 1, 64);
        if (lane == 0)
            atomicAdd(&acc[blockIdx.x & 255], (double)s);   // no fence!
    }
}

__global__ void finalize_kernel(const double* __restrict__ acc, float* __restrict__ out) {
    double v = acc[threadIdx.x];   // 256 threads, one slot each
    for (int off = 32; off > 0; off >>= 1)
        v += __shfl_down(v, off, 64);

    __shared__ double smem[4];
    const int lid = threadIdx.x & 63;
    const int wid = threadIdx.x >> 6;
    if (lid == 0) smem[wid] = v;
    __syncthreads();

    if (threadIdx.x == 0) {
        double s = smem[0] + smem[1] + smem[2] + smem[3];
        out[0] = (float)(s / 16777216.0);   // mean over 256^3
    }
}

extern "C" void kernel_launch(void* const* d_in, const int* in_sizes, int n_in,
                              void* d_out, int out_size, void* d_ws, size_t ws_size,
                              hipStream_t stream) {
    const float* x1 = (const float*)d_in[0];
    const float* x2 = (const float*)d_in[1];
    float* out = (float*)d_out;
    double* acc = (double*)d_ws;   // 256 doubles = 2 KiB scratch

    hipMemsetAsync(d_ws, 0, 256 * sizeof(double), stream);
    grad_loss_kernel<<<64 * 32, 256, 0, stream>>>(x1, x2, acc);
    finalize_kernel<<<1, 256, 0, stream>>>(acc, out);
}

// Round 5
// 150.706 us; speedup vs baseline: 1.8825x; 1.0240x over previous
//
#include <hip/hip_runtime.h>

// x volumes: [256,256,256] fp32. Row (d,h) = 256 floats = 64 float4.
// float4-unit offset: d*16384 + h*64 + lane.
//
// R11: register blocking, 2 output rows per wave. Model fit across R7-R10:
// T = S_total x L / (256 x W_res) with L~4900cy, W_res~11 pinned. R7 (3
// loads/row, LDS-shared, barriers) == R8/R10 (6 loads/row, no barriers) ==
// 46-49us: request count, barriers, occupancy caps all had ZERO effect.
// The only untouched lever is S_total (total wave-steps) -- every step pays
// the same ~4900cy latency toll regardless of content. This kernel halves
// S_total: each wave computes rows r0,r0+1, holding 4 center-plane rows +
// 2 back C-rows + 4 front rows + 4 in-flight = 28 float4 = ~132 VGPR
// (launch_bounds(256,3) caps 168; R9 lesson: never cap below natural need,
// spill = catastrophic scratch storm).
// R8 lesson: contiguous 1KB float4 loads only, no sparse edge loads.
// R3 lesson: no __threadfence / fused finalize (per-XCD L2 writeback storm).
//
// Grid: 32 htiles (8 rows each) x 32 d-chunks (8 deep) = 1024 blocks x 256.

#define D_CHUNK 8

__device__ __forceinline__ float row_term(float4 bU1, float4 bC1, float4 bV1,
                                          float4 a1, float4 c1,
                                          float4 bU2, float4 bC2, float4 bV2,
                                          float4 a2, float4 c2,
                                          float ww0, float ww1, float ww2, float ww3) {
    float l1 = __shfl_up(bC1.w, 1, 64);          // lane0: self -> finite, ww0=0
    float r1 = __shfl_down(bC1.x, 1, 64);        // lane63: self -> finite, ww3=0
    float l2 = __shfl_up(bC2.w, 1, 64);
    float r2 = __shfl_down(bC2.x, 1, 64);

    float gw, gd, gh;
    gw = c1.x - a1.x; gd = bV1.x - bU1.x; gh = bC1.y - l1;
    float m10 = __builtin_amdgcn_sqrtf(gw * gw + gd * gd + gh * gh + 1e-6f);
    gw = c1.y - a1.y; gd = bV1.y - bU1.y; gh = bC1.z - bC1.x;
    float m11 = __builtin_amdgcn_sqrtf(gw * gw + gd * gd + gh * gh + 1e-6f);
    gw = c1.z - a1.z; gd = bV1.z - bU1.z; gh = bC1.w - bC1.y;
    float m12 = __builtin_amdgcn_sqrtf(gw * gw + gd * gd + gh * gh + 1e-6f);
    gw = c1.w - a1.w; gd = bV1.w - bU1.w; gh = r1 - bC1.z;
    float m13 = __builtin_amdgcn_sqrtf(gw * gw + gd * gd + gh * gh + 1e-6f);

    gw = c2.x - a2.x; gd = bV2.x - bU2.x; gh = bC2.y - l2;
    float m20 = __builtin_amdgcn_sqrtf(gw * gw + gd * gd + gh * gh + 1e-6f);
    gw = c2.y - a2.y; gd = bV2.y - bU2.y; gh = bC2.z - bC2.x;
    float m21 = __builtin_amdgcn_sqrtf(gw * gw + gd * gd + gh * gh + 1e-6f);
    gw = c2.z - a2.z; gd = bV2.z - bU2.z; gh = bC2.w - bC2.y;
    float m22 = __builtin_amdgcn_sqrtf(gw * gw + gd * gd + gh * gh + 1e-6f);
    gw = c2.w - a2.w; gd = bV2.w - bU2.w; gh = r2 - bC2.z;
    float m23 = __builtin_amdgcn_sqrtf(gw * gw + gd * gd + gh * gh + 1e-6f);

    return ww0 * fabsf(m10 - m20)
         + ww1 * fabsf(m11 - m21)
         + ww2 * fabsf(m12 - m22)
         + ww3 * fabsf(m13 - m23);
}

__global__ __launch_bounds__(256, 3) void grad_loss_kernel(const float* __restrict__ xf1,
                                                           const float* __restrict__ xf2,
                                                           double* __restrict__ acc) {
    const float4* __restrict__ x1 = (const float4*)xf1;
    const float4* __restrict__ x2 = (const float4*)xf2;

    const int tid  = threadIdx.x;
    const int lane = tid & 63;
    const int wid  = tid >> 6;          // 0..3

    // XCD-contiguous swizzle: 1024 blocks, 8 XCDs round-robin on raw
    // blockIdx. Remap so XCD k owns 128 consecutive work-ids.
    const int orig = blockIdx.x;
    const int wg   = (orig & 7) * 128 + (orig >> 3);
    const int htile = wg & 31;          // 0..31
    const int dchk  = wg >> 5;          // 0..31

    const int r0 = 1 + htile * 8 + wid * 2;     // rows r0, r0+1 (1..256)
    const bool live0 = (r0 <= 254);
    const bool live1 = (r0 + 1 <= 254);

    const int rm  = r0 - 1;                          // 0..254, valid
    const int rc0 = (r0 <= 255) ? r0 : 255;
    const int rc1 = (r0 + 1 <= 255) ? (r0 + 1) : 255;
    const int rp  = (r0 + 2 <= 255) ? (r0 + 2) : 255;

    const int iM = rm  * 64 + lane;     // row r0-1
    const int i0 = rc0 * 64 + lane;     // row r0
    const int i1 = rc1 * 64 + lane;     // row r0+1
    const int iP = rp  * 64 + lane;     // row r0+2

    const int d0 = 1 + dchk * D_CHUNK;  // computed depths d0..d0+7 (tail >254 dead)

    // per-voxel w-axis weights (0 = excluded border, 2 = edge-replicated)
    const float ww0 = (lane == 0)  ? 0.0f : 1.0f;   // w==0
    const float ww1 = (lane == 0)  ? 2.0f : 1.0f;   // w==1
    const float ww2 = (lane == 63) ? 2.0f : 1.0f;   // w==254
    const float ww3 = (lane == 63) ? 0.0f : 1.0f;   // w==255
    const float whf0 = (r0 == 1 || r0 == 254) ? 2.0f : 1.0f;
    const float whf1 = (r0 + 1 == 1 || r0 + 1 == 254) ? 2.0f : 1.0f;

    // ---- prologue registers ----
    // back plane (d-1): C rows only; center plane (d): 4 rows; front (d+1): 4 rows.
    float4 pA01 = x1[(d0 - 1) * 16384 + i0];
    float4 pA11 = x1[(d0 - 1) * 16384 + i1];
    float4 pA02 = x2[(d0 - 1) * 16384 + i0];
    float4 pA12 = x2[(d0 - 1) * 16384 + i1];

    float4 pBm1 = x1[d0 * 16384 + iM];
    float4 pB01 = x1[d0 * 16384 + i0];
    float4 pB11 = x1[d0 * 16384 + i1];
    float4 pBp1 = x1[d0 * 16384 + iP];
    float4 pBm2 = x2[d0 * 16384 + iM];
    float4 pB02 = x2[d0 * 16384 + i0];
    float4 pB12 = x2[d0 * 16384 + i1];
    float4 pBp2 = x2[d0 * 16384 + iP];

    float4 pCm1 = x1[(d0 + 1) * 16384 + iM];    // d0+1 <= 250 always
    float4 pC01 = x1[(d0 + 1) * 16384 + i0];
    float4 pC11 = x1[(d0 + 1) * 16384 + i1];
    float4 pCp1 = x1[(d0 + 1) * 16384 + iP];
    float4 pCm2 = x2[(d0 + 1) * 16384 + iM];
    float4 pC02 = x2[(d0 + 1) * 16384 + i0];
    float4 pC12 = x2[(d0 + 1) * 16384 + i1];
    float4 pCp2 = x2[(d0 + 1) * 16384 + iP];

    float val = 0.0f;

    #pragma unroll
    for (int i = 0; i < D_CHUNK; ++i) {
        const int d  = d0 + i;
        const int dn = (d + 2 <= 255) ? (d + 2) : 255;   // prefetch depth
        const int off = dn * 16384;

        // prefetch plane d+2, rows r0-1..r0+2, both inputs (consumed next step)
        float4 qm1 = x1[off + iM];
        float4 q01 = x1[off + i0];
        float4 q11 = x1[off + i1];
        float4 qp1 = x1[off + iP];
        float4 qm2 = x2[off + iM];
        float4 q02 = x2[off + i0];
        float4 q12 = x2[off + i1];
        float4 qp2 = x2[off + iP];

        if (d <= 254) {
            const float wdf = (d == 1 || d == 254) ? 2.0f : 1.0f;
            float t = 0.0f;
            if (live0)
                t += whf0 * row_term(pBm1, pB01, pB11, pA01, pC01,
                                     pBm2, pB02, pB12, pA02, pC02,
                                     ww0, ww1, ww2, ww3);
            if (live1)
                t += whf1 * row_term(pB01, pB11, pBp1, pA11, pC11,
                                     pB02, pB12, pBp2, pA12, pC12,
                                     ww0, ww1, ww2, ww3);
            val += wdf * t;
        }

        // roll the depth pipeline: A <- B(center), B <- C, C <- Q
        pA01 = pB01; pA11 = pB11; pA02 = pB02; pA12 = pB12;
        pBm1 = pCm1; pB01 = pC01; pB11 = pC11; pBp1 = pCp1;
        pBm2 = pCm2; pB02 = pC02; pB12 = pC12; pBp2 = pCp2;
        pCm1 = qm1;  pC01 = q01;  pC11 = q11;  pCp1 = qp1;
        pCm2 = qm2;  pC02 = q02;  pC12 = q12;  pCp2 = qp2;
    }

    // wave-64 reduction
    for (int off = 32; off > 0; off >>= 1)
        val += __shfl_down(val, off, 64);

    __shared__ float smem[4];
    if (lane == 0) smem[wid] = val;
    __syncthreads();

    if (wid == 0) {
        float s = (lane < 4) ? smem[lane] : 0.0f;
        s += __shfl_down(s, 2, 64);
        s += __shfl_down(s, 1, 64);
        if (lane == 0)
            atomicAdd(&acc[blockIdx.x & 255], (double)s);   // no fence!
    }
}

__global__ void finalize_kernel(const double* __restrict__ acc, float* __restrict__ out) {
    double v = acc[threadIdx.x];   // 256 threads, one slot each
    for (int off = 32; off > 0; off >>= 1)
        v += __shfl_down(v, off, 64);

    __shared__ double smem[4];
    const int lid = threadIdx.x & 63;
    const int wid = threadIdx.x >> 6;
    if (lid == 0) smem[wid] = v;
    __syncthreads();

    if (threadIdx.x == 0) {
        double s = smem[0] + smem[1] + smem[2] + smem[3];
        out[0] = (float)(s / 16777216.0);   // mean over 256^3
    }
}

extern "C" void kernel_launch(void* const* d_in, const int* in_sizes, int n_in,
                              void* d_out, int out_size, void* d_ws, size_t ws_size,
                              hipStream_t stream) {
    const float* x1 = (const float*)d_in[0];
    const float* x2 = (const float*)d_in[1];
    float* out = (float*)d_out;
    double* acc = (double*)d_ws;   // 256 doubles = 2 KiB scratch

    hipMemsetAsync(d_ws, 0, 256 * sizeof(double), stream);
    grad_loss_kernel<<<32 * 32, 256, 0, stream>>>(x1, x2, acc);
    finalize_kernel<<<1, 256, 0, stream>>>(acc, out);
}

// Round 6
// 149.287 us; speedup vs baseline: 1.9004x; 1.0095x over previous
//
#include <hip/hip_runtime.h>

// x volumes: [256,256,256] fp32. Row (d,h) = 256 floats = 64 float4.
// float4-unit offset: d*16384 + h*64 + lane.
//
// R12: fused finalize via last-block-done. R7-R11 establish: six structures
// (LDS/no-LDS, barriers/none, 3-8 loads/step, occ 24-78%, wave-steps 2x
// swing) ALL pin at 45-50us; unique 128MB read / 47us = 2.7 TB/s whether
// L3-resident (warm FETCH~0) or HBM-cold -> common stage is the L2-fill
// (miss-service) path, ~1.1 lines/cy/XCD. Little's-law closed loop: latency
// is the queue, not the constraint; nothing that preserves unique bytes can
// move the kernel. Remaining controllable cost: our own 3 graph nodes.
// This round drops the finalize dispatch: last block (atomic counter) does
// the 256-slot reduction in-kernel. Device-scope atomics only (R3 lesson:
// no __threadfence storm); explicit s_waitcnt vmcnt(0) orders each block's
// acc atomicAdd before its counter atomicAdd; last block reads acc with
// atomicAdd(p,0.0) (coherent point reads, no stale L1).
// R9 lesson: never cap launch_bounds below natural VGPR need.
// R8 lesson: contiguous 1KB float4 loads only.
//
// Grid: 32 htiles (8 rows each) x 32 d-chunks (8 deep) = 1024 blocks x 256.

#define D_CHUNK 8
#define NBLOCKS 1024

__device__ __forceinline__ float row_term(float4 bU1, float4 bC1, float4 bV1,
                                          float4 a1, float4 c1,
                                          float4 bU2, float4 bC2, float4 bV2,
                                          float4 a2, float4 c2,
                                          float ww0, float ww1, float ww2, float ww3) {
    float l1 = __shfl_up(bC1.w, 1, 64);          // lane0: self -> finite, ww0=0
    float r1 = __shfl_down(bC1.x, 1, 64);        // lane63: self -> finite, ww3=0
    float l2 = __shfl_up(bC2.w, 1, 64);
    float r2 = __shfl_down(bC2.x, 1, 64);

    float gw, gd, gh;
    gw = c1.x - a1.x; gd = bV1.x - bU1.x; gh = bC1.y - l1;
    float m10 = __builtin_amdgcn_sqrtf(gw * gw + gd * gd + gh * gh + 1e-6f);
    gw = c1.y - a1.y; gd = bV1.y - bU1.y; gh = bC1.z - bC1.x;
    float m11 = __builtin_amdgcn_sqrtf(gw * gw + gd * gd + gh * gh + 1e-6f);
    gw = c1.z - a1.z; gd = bV1.z - bU1.z; gh = bC1.w - bC1.y;
    float m12 = __builtin_amdgcn_sqrtf(gw * gw + gd * gd + gh * gh + 1e-6f);
    gw = c1.w - a1.w; gd = bV1.w - bU1.w; gh = r1 - bC1.z;
    float m13 = __builtin_amdgcn_sqrtf(gw * gw + gd * gd + gh * gh + 1e-6f);

    gw = c2.x - a2.x; gd = bV2.x - bU2.x; gh = bC2.y - l2;
    float m20 = __builtin_amdgcn_sqrtf(gw * gw + gd * gd + gh * gh + 1e-6f);
    gw = c2.y - a2.y; gd = bV2.y - bU2.y; gh = bC2.z - bC2.x;
    float m21 = __builtin_amdgcn_sqrtf(gw * gw + gd * gd + gh * gh + 1e-6f);
    gw = c2.z - a2.z; gd = bV2.z - bU2.z; gh = bC2.w - bC2.y;
    float m22 = __builtin_amdgcn_sqrtf(gw * gw + gd * gd + gh * gh + 1e-6f);
    gw = c2.w - a2.w; gd = bV2.w - bU2.w; gh = r2 - bC2.z;
    float m23 = __builtin_amdgcn_sqrtf(gw * gw + gd * gd + gh * gh + 1e-6f);

    return ww0 * fabsf(m10 - m20)
         + ww1 * fabsf(m11 - m21)
         + ww2 * fabsf(m12 - m22)
         + ww3 * fabsf(m13 - m23);
}

__global__ __launch_bounds__(256, 3) void grad_loss_kernel(const float* __restrict__ xf1,
                                                           const float* __restrict__ xf2,
                                                           double* __restrict__ acc,
                                                           unsigned int* __restrict__ counter,
                                                           float* __restrict__ out) {
    const float4* __restrict__ x1 = (const float4*)xf1;
    const float4* __restrict__ x2 = (const float4*)xf2;

    const int tid  = threadIdx.x;
    const int lane = tid & 63;
    const int wid  = tid >> 6;          // 0..3

    // XCD-contiguous swizzle: 1024 blocks, 8 XCDs round-robin on raw
    // blockIdx. Remap so XCD k owns 128 consecutive work-ids.
    const int orig = blockIdx.x;
    const int wg   = (orig & 7) * 128 + (orig >> 3);
    const int htile = wg & 31;          // 0..31
    const int dchk  = wg >> 5;          // 0..31

    const int r0 = 1 + htile * 8 + wid * 2;     // rows r0, r0+1 (1..256)
    const bool live0 = (r0 <= 254);
    const bool live1 = (r0 + 1 <= 254);

    const int rm  = r0 - 1;                          // 0..254, valid
    const int rc0 = (r0 <= 255) ? r0 : 255;
    const int rc1 = (r0 + 1 <= 255) ? (r0 + 1) : 255;
    const int rp  = (r0 + 2 <= 255) ? (r0 + 2) : 255;

    const int iM = rm  * 64 + lane;     // row r0-1
    const int i0 = rc0 * 64 + lane;     // row r0
    const int i1 = rc1 * 64 + lane;     // row r0+1
    const int iP = rp  * 64 + lane;     // row r0+2

    const int d0 = 1 + dchk * D_CHUNK;  // computed depths d0..d0+7 (tail >254 dead)

    // per-voxel w-axis weights (0 = excluded border, 2 = edge-replicated)
    const float ww0 = (lane == 0)  ? 0.0f : 1.0f;   // w==0
    const float ww1 = (lane == 0)  ? 2.0f : 1.0f;   // w==1
    const float ww2 = (lane == 63) ? 2.0f : 1.0f;   // w==254
    const float ww3 = (lane == 63) ? 0.0f : 1.0f;   // w==255
    const float whf0 = (r0 == 1 || r0 == 254) ? 2.0f : 1.0f;
    const float whf1 = (r0 + 1 == 1 || r0 + 1 == 254) ? 2.0f : 1.0f;

    // ---- prologue registers ----
    float4 pA01 = x1[(d0 - 1) * 16384 + i0];
    float4 pA11 = x1[(d0 - 1) * 16384 + i1];
    float4 pA02 = x2[(d0 - 1) * 16384 + i0];
    float4 pA12 = x2[(d0 - 1) * 16384 + i1];

    float4 pBm1 = x1[d0 * 16384 + iM];
    float4 pB01 = x1[d0 * 16384 + i0];
    float4 pB11 = x1[d0 * 16384 + i1];
    float4 pBp1 = x1[d0 * 16384 + iP];
    float4 pBm2 = x2[d0 * 16384 + iM];
    float4 pB02 = x2[d0 * 16384 + i0];
    float4 pB12 = x2[d0 * 16384 + i1];
    float4 pBp2 = x2[d0 * 16384 + iP];

    float4 pCm1 = x1[(d0 + 1) * 16384 + iM];    // d0+1 <= 250 always
    float4 pC01 = x1[(d0 + 1) * 16384 + i0];
    float4 pC11 = x1[(d0 + 1) * 16384 + i1];
    float4 pCp1 = x1[(d0 + 1) * 16384 + iP];
    float4 pCm2 = x2[(d0 + 1) * 16384 + iM];
    float4 pC02 = x2[(d0 + 1) * 16384 + i0];
    float4 pC12 = x2[(d0 + 1) * 16384 + i1];
    float4 pCp2 = x2[(d0 + 1) * 16384 + iP];

    float val = 0.0f;

    #pragma unroll
    for (int i = 0; i < D_CHUNK; ++i) {
        const int d  = d0 + i;
        const int dn = (d + 2 <= 255) ? (d + 2) : 255;   // prefetch depth
        const int off = dn * 16384;

        // prefetch plane d+2, rows r0-1..r0+2, both inputs (consumed next step)
        float4 qm1 = x1[off + iM];
        float4 q01 = x1[off + i0];
        float4 q11 = x1[off + i1];
        float4 qp1 = x1[off + iP];
        float4 qm2 = x2[off + iM];
        float4 q02 = x2[off + i0];
        float4 q12 = x2[off + i1];
        float4 qp2 = x2[off + iP];

        if (d <= 254) {
            const float wdf = (d == 1 || d == 254) ? 2.0f : 1.0f;
            float t = 0.0f;
            if (live0)
                t += whf0 * row_term(pBm1, pB01, pB11, pA01, pC01,
                                     pBm2, pB02, pB12, pA02, pC02,
                                     ww0, ww1, ww2, ww3);
            if (live1)
                t += whf1 * row_term(pB01, pB11, pBp1, pA11, pC11,
                                     pB02, pB12, pBp2, pA12, pC12,
                                     ww0, ww1, ww2, ww3);
            val += wdf * t;
        }

        // roll the depth pipeline: A <- B(center), B <- C, C <- Q
        pA01 = pB01; pA11 = pB11; pA02 = pB02; pA12 = pB12;
        pBm1 = pCm1; pB01 = pC01; pB11 = pC11; pBp1 = pCp1;
        pBm2 = pCm2; pB02 = pC02; pB12 = pC12; pBp2 = pCp2;
        pCm1 = qm1;  pC01 = q01;  pC11 = q11;  pCp1 = qp1;
        pCm2 = qm2;  pC02 = q02;  pC12 = q12;  pCp2 = qp2;
    }

    // ---- block reduction ----
    for (int off = 32; off > 0; off >>= 1)
        val += __shfl_down(val, off, 64);

    __shared__ float smem[4];
    __shared__ int last_flag;
    if (lane == 0) smem[wid] = val;
    __syncthreads();

    if (tid == 0) {
        float s = smem[0] + smem[1] + smem[2] + smem[3];
        atomicAdd(&acc[wg & 255], (double)s);            // device-scope
        // order: acc add must reach the coherent point before counter add
        asm volatile("s_waitcnt vmcnt(0)" ::: "memory");
        unsigned int old = atomicAdd(counter, 1u);
        last_flag = (old == NBLOCKS - 1) ? 1 : 0;
    }
    __syncthreads();

    // ---- last block: fused finalize (no extra dispatch) ----
    if (last_flag) {
        // coherent read of all 256 slots (atomic op -> bypasses stale L1)
        double v = atomicAdd(&acc[tid], 0.0);
        for (int off = 32; off > 0; off >>= 1)
            v += __shfl_down(v, off, 64);

        __shared__ double dsm[4];
        if (lane == 0) dsm[wid] = v;
        __syncthreads();

        if (tid == 0) {
            double s = dsm[0] + dsm[1] + dsm[2] + dsm[3];
            out[0] = (float)(s / 16777216.0);   // mean over 256^3
        }
    }
}

extern "C" void kernel_launch(void* const* d_in, const int* in_sizes, int n_in,
                              void* d_out, int out_size, void* d_ws, size_t ws_size,
                              hipStream_t stream) {
    const float* x1 = (const float*)d_in[0];
    const float* x2 = (const float*)d_in[1];
    float* out = (float*)d_out;
    double* acc = (double*)d_ws;                         // 256 doubles
    unsigned int* counter = (unsigned int*)((char*)d_ws + 256 * sizeof(double));

    hipMemsetAsync(d_ws, 0, 256 * sizeof(double) + sizeof(unsigned int), stream);
    grad_loss_kernel<<<NBLOCKS, 256, 0, stream>>>(x1, x2, acc, counter, out);
}